// Round 5
// baseline (368.818 us; speedup 1.0000x reference)
//
#include <hip/hip_runtime.h>
#include <math.h>

#define AR_P 48
#define FLEN 168
#define HISTLEN 336
#define TPC 24               // forecast steps per chunk
#define NCH 7                // chunks (7*24 = 168)
#define CH_STRIDE 1176       // floats per chunk image: 48*24 W + 24 cc (byte 4704, 16B-aligned)
#define STP 28               // st2 row stride in floats (112 B, 16B-aligned)

// ws layout (fp32), chunk-packed for contiguous scalar loads:
//   chunk c at ws + c*1176:  [k*24 + j] = W[k][t=24c+j]   (1152 floats)
//                            [1152 + j] = cc[t=24c+j]     (24 floats)
__global__ void k_coeffs(const float* __restrict__ phi,
                         const float* __restrict__ bias,
                         const float* __restrict__ mu_p,
                         const float* __restrict__ sigma_p,
                         float* __restrict__ ws) {
    const int k = threadIdx.x;  // 64 threads, 1 wave
    const float mu     = mu_p[0];
    const float sigma  = sigma_p[0];
    const float bias_f = bias[0];
    const float phik = (k < AR_P) ? phi[k] : 0.0f;

    float r = phik;     // r_0 = phi
    float csum = 0.0f;  // sum_{m<t} r_m[47]
    int c = 0, j = 0;
    for (int t = 0; t < FLEN; ++t) {
        if (k < AR_P) ws[c * CH_STRIDE + k * TPC + j] = r;
        if (k == 0)   ws[c * CH_STRIDE + AR_P * TPC + j] =
                          bias_f * (1.0f + csum) * sigma + mu;
        float r47 = __shfl(r, AR_P - 1, 64);
        csum += r47;
        float up = __shfl_up(r, 1, 64);
        float rn = (k == 0 ? 0.0f : up) + r47 * phik;
        r = (k < AR_P) ? rn : 0.0f;
        if (++j == TPC) { j = 0; ++c; }
    }
}

// Wave-autonomous: 64-thread blocks, 1 row/thread, NO block-wide phase barriers.
// y[48] in registers; W/cc via uniform s_load (contiguous chunk image, sL1-hot);
// per-chunk 64x24 transpose through a private 7.2 KB LDS buffer (same-wave
// lgkmcnt sync only); 6 coalesced mu-float4 + 6 coalesced logvar-float4 stores
// per chunk -> continuous write stream across 8 desynced waves/CU.
__global__ __launch_bounds__(64) void k_main(
    const float* __restrict__ enc_l,
    const float* __restrict__ ws,
    const float* __restrict__ mu_p,
    const float* __restrict__ ls2,
    const float* __restrict__ sg,
    float* __restrict__ out,  // [2*B*168]: mu then logvar
    int B) {
    const int lane = threadIdx.x;
    const int r0   = blockIdx.x * 64;
    const int row  = r0 + lane;
    const bool full  = (r0 + 64) <= B;   // uniform
    const bool valid = row < B;

    const float mu = mu_p[0];
    const float lv = ls2[0] + 2.0f * logf(sg[0]);

    // ---- y tail -> registers: 12 float4 loads (3 exact cache lines per row,
    // same-line reuse across back-to-back instrs merges in L1) ----
    float y[AR_P];
    {
        const float4* yp = reinterpret_cast<const float4*>(
            enc_l + (size_t)row * HISTLEN + (HISTLEN - AR_P));
#pragma unroll
        for (int i = 0; i < AR_P / 4; ++i) {
            float4 q = valid ? yp[i] : make_float4(0.f, 0.f, 0.f, 0.f);
            y[4 * i + 0] = q.x - mu;
            y[4 * i + 1] = q.y - mu;
            y[4 * i + 2] = q.z - mu;
            y[4 * i + 3] = q.w - mu;
        }
    }

    __shared__ float st2[64 * STP];

    // store mapping, loop-invariant across chunks: f4 slot e*64+lane -> (row,q)
    int re[6], qe[6];
#pragma unroll
    for (int e = 0; e < 6; ++e) {
        int i = e * 64 + lane;
        re[e] = i / 6;
        qe[e] = i - re[e] * 6;
    }

    float* const mu_out = out;
    float* const lv_out = out + (size_t)B * FLEN;
    const float4 lvv = make_float4(lv, lv, lv, lv);

    for (int c = 0; c < NCH; ++c) {
        const float* W = ws + c * CH_STRIDE;  // uniform (no tid) -> s_load
        float acc[TPC];
#pragma unroll
        for (int j = 0; j < TPC; ++j) acc[j] = 0.0f;
#pragma unroll
        for (int k = 0; k < AR_P; ++k) {
            const float yk = y[k];  // register, static index
#pragma unroll
            for (int j = 0; j < TPC; ++j)
                acc[j] = fmaf(W[k * TPC + j], yk, acc[j]);  // SGPR * VGPR + VGPR
        }
#pragma unroll
        for (int j = 0; j < TPC; ++j) acc[j] += W[AR_P * TPC + j];  // + cc

        // ---- transpose via private LDS (1-wave block: barrier ~= waitcnt) ----
        __syncthreads();  // WAR vs previous chunk's reads
#pragma unroll
        for (int e = 0; e < 6; ++e) {
            float4 v = make_float4(acc[4 * e + 0], acc[4 * e + 1],
                                   acc[4 * e + 2], acc[4 * e + 3]);
            *reinterpret_cast<float4*>(&st2[lane * STP + 4 * e]) = v;
        }
        __syncthreads();

        // ---- mu chunk stores: 6 lanes/row x 96 B contiguous, ~21 lines/instr ----
#pragma unroll
        for (int e = 0; e < 6; ++e) {
            float4 v = *reinterpret_cast<const float4*>(
                &st2[re[e] * STP + 4 * qe[e]]);
            if (full || r0 + re[e] < B)
                *reinterpret_cast<float4*>(
                    mu_out + (size_t)(r0 + re[e]) * FLEN + c * TPC + 4 * qe[e]) = v;
        }

        // ---- logvar sweep: 6 fully-coalesced float4 per chunk over the wave's
        // contiguous 43 KB lv region (spreads write demand evenly) ----
        if (full) {
            float4* dst = reinterpret_cast<float4*>(lv_out + (size_t)r0 * FLEN);
#pragma unroll
            for (int e = 0; e < 6; ++e) dst[(c * 6 + e) * 64 + lane] = lvv;
        }
    }

    if (!full) {  // tail block: guarded logvar fill
        const int n4 = (B - r0) * (FLEN / 4);
        float4* dst = reinterpret_cast<float4*>(lv_out + (size_t)r0 * FLEN);
        for (int i = lane; i < n4; i += 64) dst[i] = lvv;
    }
}

extern "C" void kernel_launch(void* const* d_in, const int* in_sizes, int n_in,
                              void* d_out, int out_size, void* d_ws, size_t ws_size,
                              hipStream_t stream) {
    const float* enc_l = (const float*)d_in[0];
    // d_in[1..3] = enc_t, enc_w, enc_s (unused by the reference)
    const float* phi  = (const float*)d_in[4];
    const float* bias = (const float*)d_in[5];
    const float* ls2  = (const float*)d_in[6];
    const float* mu   = (const float*)d_in[7];
    const float* sg   = (const float*)d_in[8];
    float* ws  = (float*)d_ws;
    float* out = (float*)d_out;
    const int B = in_sizes[0] / HISTLEN;

    hipLaunchKernelGGL(k_coeffs, dim3(1), dim3(64), 0, stream,
                       phi, bias, mu, sg, ws);
    hipLaunchKernelGGL(k_main, dim3((B + 63) / 64), dim3(64), 0, stream,
                       enc_l, ws, mu, ls2, sg, out, B);
}

// Round 6
// 310.733 us; speedup vs baseline: 1.1869x; 1.1869x over previous
//
#include <hip/hip_runtime.h>
#include <math.h>

#define AR_P 48
#define FLEN 168
#define HISTLEN 336
#define ROWS 128      // batch rows per block (2 per thread)
#define NTHREADS 448  // 7 waves
#define TPW 24        // forecast steps per wave (168/7); 24 floats = 6 float4, 16B-aligned
#define HALF 64

// ws layout (fp32): [0, 8064) Wt[k][t] (transposed coeffs), [8064, 8232) cc[t]

// One wave. Companion-matrix power recurrence:
//   r_0 = phi;  r_{t+1}[k] = r_t[k-1] + r_t[47]*phi[k]   (r_t[-1] == 0)
//   mu_orig[b,t] = cc[t] + sum_k Wt[k,t]*(y[b,k]-mu)   (sigma cancels in W)
__global__ void k_coeffs(const float* __restrict__ phi,
                         const float* __restrict__ bias,
                         const float* __restrict__ mu_p,
                         const float* __restrict__ sigma_p,
                         float* __restrict__ ws) {
    const int k = threadIdx.x;  // 64 threads, 1 wave
    float* Wt = ws;             // [48][168]
    float* cc = ws + AR_P * FLEN;
    const float mu     = mu_p[0];
    const float sigma  = sigma_p[0];
    const float bias_f = bias[0];
    const float phik = (k < AR_P) ? phi[k] : 0.0f;

    float r = phik;     // r_0 = phi
    float csum = 0.0f;  // sum_{m<t} r_m[47]
    for (int t = 0; t < FLEN; ++t) {
        if (k < AR_P) Wt[k * FLEN + t] = r;          // transposed store
        if (k == 0)   cc[t] = bias_f * (1.0f + csum) * sigma + mu;
        float r47 = __shfl(r, AR_P - 1, 64);
        csum += r47;
        float up = __shfl_up(r, 1, 64);
        float rn = (k == 0 ? 0.0f : up) + r47 * phik;
        r = (k < AR_P) ? rn : 0.0f;
    }
}

// Block = 448 threads (7 waves), 128 rows (2/thread), all 168 t's, fused logvar.
// (a) readfirstlane -> W/cc provably wave-uniform -> s_load (scalar cache);
// (b) ym/so share one 43.7 KB LDS buffer -> 3 blocks/CU;
// (c) logvar fill at the VERY END, after the last barrier: hipcc drains
//     vmcnt(0) at every s_barrier, so 129 KB of the block's 172 KB of writes
//     (pass B + logvar) now issue after the final barrier and never stall a
//     wave -- they complete asynchronously at kernel end.
__global__ __launch_bounds__(NTHREADS, 5) void k_main(
    const float* __restrict__ enc_l,
    const float* __restrict__ ws,
    const float* __restrict__ mu_p,
    const float* __restrict__ ls2,
    const float* __restrict__ sg,
    float* __restrict__ out,  // [2*B*168]: mu then logvar
    int B) {
    // union: ym [48][130] (25.0 KB, live until k-loop ends)
    //        so [168][65] (43.7 KB, live after)  -> one 43.7 KB buffer
    __shared__ __align__(16) char smem_raw[FLEN * (HALF + 1) * sizeof(float)];
    float (*ym)[ROWS + 2] = reinterpret_cast<float (*)[ROWS + 2]>(smem_raw);
    float (*so)[HALF + 1] = reinterpret_cast<float (*)[HALF + 1]>(smem_raw);

    const int tid = threadIdx.x;
    const int r0  = blockIdx.x * ROWS;
    const int rows_here = min(ROWS, B - r0);
    const float mu = mu_p[0];

    // ---- coalesced cooperative tail load: 128 rows x 12 float4 ----
    for (int id = tid; id < rows_here * 12; id += NTHREADS) {
        int row = id / 12, q = id - row * 12;
        float4 qv = *reinterpret_cast<const float4*>(
            enc_l + (size_t)(r0 + row) * HISTLEN + (HISTLEN - AR_P) + q * 4);
        ym[q * 4 + 0][row] = qv.x - mu;
        ym[q * 4 + 1][row] = qv.y - mu;
        ym[q * 4 + 2][row] = qv.z - mu;
        ym[q * 4 + 3][row] = qv.w - mu;
    }
    __syncthreads();  // only the 12 tail loads to wait on (no store drain here)

    // ---- compute: wave w owns t in [24w, 24w+24), lane = row, 2 rows/thread ----
    const int lane = tid & 63;
    // readfirstlane -> compiler-provable wave-uniform: W/cc loads become s_load
    const int t0 = __builtin_amdgcn_readfirstlane((tid >> 6) * TPW);
    const float* Wt = ws;
    const float* cc = ws + AR_P * FLEN;

    float acc0[TPW], acc1[TPW];
    {
        const float4* cp = reinterpret_cast<const float4*>(cc + t0);  // 16B-aligned
#pragma unroll
        for (int jq = 0; jq < TPW / 4; ++jq) {
            float4 c4 = cp[jq];
            acc0[jq * 4 + 0] = c4.x; acc1[jq * 4 + 0] = c4.x;
            acc0[jq * 4 + 1] = c4.y; acc1[jq * 4 + 1] = c4.y;
            acc0[jq * 4 + 2] = c4.z; acc1[jq * 4 + 2] = c4.z;
            acc0[jq * 4 + 3] = c4.w; acc1[jq * 4 + 3] = c4.w;
        }
    }
#pragma unroll 2
    for (int k = 0; k < AR_P; ++k) {
        const float y0 = ym[k][lane];        // 2-way LDS (free)
        const float y1 = ym[k][lane + HALF];
        const float4* wp = reinterpret_cast<const float4*>(Wt + k * FLEN + t0);
#pragma unroll
        for (int jq = 0; jq < TPW / 4; ++jq) {
            float4 w4 = wp[jq];  // uniform addr -> s_load_dwordx4, SGPR operand
            acc0[jq * 4 + 0] = fmaf(w4.x, y0, acc0[jq * 4 + 0]);
            acc0[jq * 4 + 1] = fmaf(w4.y, y0, acc0[jq * 4 + 1]);
            acc0[jq * 4 + 2] = fmaf(w4.z, y0, acc0[jq * 4 + 2]);
            acc0[jq * 4 + 3] = fmaf(w4.w, y0, acc0[jq * 4 + 3]);
            acc1[jq * 4 + 0] = fmaf(w4.x, y1, acc1[jq * 4 + 0]);
            acc1[jq * 4 + 1] = fmaf(w4.y, y1, acc1[jq * 4 + 1]);
            acc1[jq * 4 + 2] = fmaf(w4.z, y1, acc1[jq * 4 + 2]);
            acc1[jq * 4 + 3] = fmaf(w4.w, y1, acc1[jq * 4 + 3]);
        }
    }
    __syncthreads();  // ym dead from here; so may overwrite the shared buffer

    // store index mapping, computed once (div-free afterwards)
    const int row_i = tid / FLEN;           // 0..2
    const int t_i   = tid - row_i * FLEN;
    const int nA = min(rows_here, HALF) * FLEN;

    // ---- pass A: stage + store rows [0, 64) ----
#pragma unroll
    for (int j = 0; j < TPW; ++j) so[t0 + j][lane] = acc0[j];
    __syncthreads();
    {
        float* dst = out + (size_t)r0 * FLEN;  // block's contiguous mu span
        int i = tid, row = row_i, t = t_i;
#pragma unroll 4
        for (int p = 0; p < (HALF * FLEN) / NTHREADS; ++p) {  // 24
            if (i < nA) dst[i] = so[t][row];  // consecutive banks: conflict-free
            i += NTHREADS;
            row += 2; t += NTHREADS - 2 * FLEN;               // +112
            if (t >= FLEN) { t -= FLEN; ++row; }
        }
    }
    __syncthreads();  // WAR: pass B overwrites so (drains pass-A stores, 43 KB)

    // ---- pass B: stage + store rows [64, 128) ----
#pragma unroll
    for (int j = 0; j < TPW; ++j) so[t0 + j][lane] = acc1[j];
    __syncthreads();
    if (rows_here > HALF) {
        float* dst = out + ((size_t)r0 + HALF) * FLEN;
        const int nB = (rows_here - HALF) * FLEN;
        int i = tid, row = row_i, t = t_i;
#pragma unroll 4
        for (int p = 0; p < (HALF * FLEN) / NTHREADS; ++p) {
            if (i < nB) dst[i] = so[t][row];
            i += NTHREADS;
            row += 2; t += NTHREADS - 2 * FLEN;
            if (t >= FLEN) { t -= FLEN; ++row; }
        }
    }

    // ---- logvar region LAST: after the final barrier, so these 86 KB of
    // stores (plus pass B's 43 KB) never sit inside a vmcnt(0) drain ----
    {
        const float lv = ls2[0] + 2.0f * logf(sg[0]);
        const float4 v = make_float4(lv, lv, lv, lv);
        float4* dst = reinterpret_cast<float4*>(
            out + (size_t)B * FLEN + (size_t)r0 * FLEN);
        const int n4 = rows_here * (FLEN / 4);
        for (int i = tid; i < n4; i += NTHREADS) dst[i] = v;
    }
}

extern "C" void kernel_launch(void* const* d_in, const int* in_sizes, int n_in,
                              void* d_out, int out_size, void* d_ws, size_t ws_size,
                              hipStream_t stream) {
    const float* enc_l = (const float*)d_in[0];
    // d_in[1..3] = enc_t, enc_w, enc_s (unused by the reference)
    const float* phi  = (const float*)d_in[4];
    const float* bias = (const float*)d_in[5];
    const float* ls2  = (const float*)d_in[6];
    const float* mu   = (const float*)d_in[7];
    const float* sg   = (const float*)d_in[8];
    float* ws  = (float*)d_ws;
    float* out = (float*)d_out;
    const int B = in_sizes[0] / HISTLEN;

    hipLaunchKernelGGL(k_coeffs, dim3(1), dim3(64), 0, stream,
                       phi, bias, mu, sg, ws);
    hipLaunchKernelGGL(k_main, dim3((B + ROWS - 1) / ROWS), dim3(NTHREADS), 0, stream,
                       enc_l, ws, mu, ls2, sg, out, B);
}